// Round 1
// baseline (34915.796 us; speedup 1.0000x reference)
//
#include <hip/hip_runtime.h>
#include <math.h>

#define S_LEN 2048
#define HID_N 4096
#define NH 32
#define NKV 8
#define HD 128
#define INIT_N 128
#define RECENT_N 512
#define HEAVY_N 512

// ---------------- fp32 tiled GEMM: C[M][N] = A[M][K] @ B[K][N], row-major ----
#define BM 64
#define BN 64
#define BK 16

__global__ __launch_bounds__(256) void gemm_f32(const float* __restrict__ A,
                                                const float* __restrict__ B,
                                                float* __restrict__ C,
                                                int M, int N, int K) {
  __shared__ float As[BK][BM];   // transposed A tile: As[k][m]
  __shared__ float Bs[BK][BN];
  const int tid = threadIdx.x;
  const int tx = tid & 15;   // N direction
  const int ty = tid >> 4;   // M direction
  const int bm = blockIdx.y * BM;
  const int bn = blockIdx.x * BN;
  const int a_r = tid >> 2;          // 0..63
  const int a_c = (tid & 3) << 2;    // 0,4,8,12
  const int b_r = tid >> 4;          // 0..15
  const int b_c = (tid & 15) << 2;   // 0..60

  float acc[4][4] = {};
  for (int k0 = 0; k0 < K; k0 += BK) {
    float4 av = *(const float4*)(A + (size_t)(bm + a_r) * K + (k0 + a_c));
    float4 bv = *(const float4*)(B + (size_t)(k0 + b_r) * N + (bn + b_c));
    As[a_c + 0][a_r] = av.x;
    As[a_c + 1][a_r] = av.y;
    As[a_c + 2][a_r] = av.z;
    As[a_c + 3][a_r] = av.w;
    *(float4*)&Bs[b_r][b_c] = bv;
    __syncthreads();
#pragma unroll
    for (int kk = 0; kk < BK; ++kk) {
      float4 a = *(const float4*)&As[kk][ty << 2];
      float4 b = *(const float4*)&Bs[kk][tx << 2];
      float ar[4] = {a.x, a.y, a.z, a.w};
      float br[4] = {b.x, b.y, b.z, b.w};
#pragma unroll
      for (int i = 0; i < 4; ++i)
#pragma unroll
        for (int j = 0; j < 4; ++j) acc[i][j] = fmaf(ar[i], br[j], acc[i][j]);
    }
    __syncthreads();
  }
#pragma unroll
  for (int i = 0; i < 4; ++i) {
    float4 o = make_float4(acc[i][0], acc[i][1], acc[i][2], acc[i][3]);
    *(float4*)(C + (size_t)(bm + (ty << 2) + i) * N + bn + (tx << 2)) = o;
  }
}

// ---------------- RoPE in place: x is [S][nheads*HD], pairs (i, i+64) --------
__global__ __launch_bounds__(256) void rope_f32(float* __restrict__ x, int nheads) {
  int idx = blockIdx.x * 256 + threadIdx.x;
  int i = idx & 63;            // rotary pair index 0..63
  int rest = idx >> 6;
  int hh = rest % nheads;
  int s = rest / nheads;
  if (s >= S_LEN) return;
  float* p = x + ((size_t)s * nheads + hh) * HD;
  float inv = (float)(1.0 / pow(10000.0, (double)(2 * i) / 128.0));
  float ang = (float)s * inv;
  float c = cosf(ang);
  float sn = sinf(ang);
  float x1 = p[i];
  float x2 = p[i + 64];
  p[i] = x1 * c - x2 * sn;
  p[i + 64] = x2 * c + x1 * sn;
}

// ---------------- fused heavy-hitter attention, one block per (qi, head) -----
__device__ __forceinline__ unsigned fkey(float f) {
  // order-preserving float -> uint (larger float => larger uint)
  unsigned u = __float_as_uint(f);
  return (u & 0x80000000u) ? ~u : (u | 0x80000000u);
}

__global__ __launch_bounds__(256) void attn_kernel(const float* __restrict__ q,
                                                   const float* __restrict__ k,
                                                   const float* __restrict__ v,
                                                   float* __restrict__ ao) {
  const int qi = blockIdx.x;
  const int h = blockIdx.y;
  const int g = h >> 2;            // NH/NKV = 4 -> kv head
  const int tid = threadIdx.x;
  const int nk = qi + 1;

  __shared__ float qs[HD];
  __shared__ float sc[S_LEN];
  __shared__ unsigned char sel[S_LEN];
  __shared__ unsigned int hist[256];
  __shared__ float red[256];
  __shared__ float pv[2][HD];
  __shared__ unsigned int s_prefix;
  __shared__ unsigned int s_remaining;

  if (tid < HD) qs[tid] = q[((size_t)qi * NH + h) * HD + tid];
  __syncthreads();

  // ---- scores for causal keys, init base-mask ----
  for (int ki = tid; ki < nk; ki += 256) {
    const float4* kr = (const float4*)(k + ((size_t)ki * NKV + g) * HD);
    const float4* qr = (const float4*)qs;
    float dot = 0.f;
#pragma unroll
    for (int j = 0; j < HD / 4; ++j) {
      float4 a = qr[j];
      float4 b = kr[j];
      dot += a.x * b.x + a.y * b.y + a.z * b.z + a.w * b.w;
    }
    sc[ki] = dot * 0.08838834764831845f;  // 1/sqrt(128)
    bool middle = (ki >= INIT_N) && (ki + RECENT_N <= qi);
    sel[ki] = middle ? 0 : 1;  // base = causal & !middle
  }
  __syncthreads();

  // ---- heavy-hitter selection over middle window [INIT, qi-RECENT] ----
  const int m = qi - RECENT_N - INIT_N + 1;
  const int mlo = INIT_N;
  const int mhi = qi - RECENT_N;
  if (m > 0 && m <= HEAVY_N) {
    // fewer middle elements than HEAVY: all selected
    for (int ki = mlo + tid; ki <= mhi; ki += 256) sel[ki] = 1;
    __syncthreads();
  } else if (m > HEAVY_N) {
    // radix select: find exact key value of the HEAVY-th largest
    if (tid == 0) { s_prefix = 0; s_remaining = HEAVY_N; }
    __syncthreads();
    for (int shift = 24; shift >= 0; shift -= 8) {
      hist[tid] = 0;
      __syncthreads();
      const unsigned pf = s_prefix;
      const unsigned hm = (shift == 24) ? 0u : (0xFFFFFFFFu << (shift + 8));
      for (int ki = mlo + tid; ki <= mhi; ki += 256) {
        unsigned u = fkey(sc[ki]);
        if ((u & hm) == pf) atomicAdd(&hist[(u >> shift) & 255u], 1u);
      }
      __syncthreads();
      if (tid == 0) {
        unsigned rem = s_remaining;
        int b = 255;
        for (; b > 0; --b) {
          unsigned c = hist[b];
          if (c >= rem) break;
          rem -= c;
        }
        s_prefix = pf | ((unsigned)b << shift);
        s_remaining = rem;
      }
      __syncthreads();
    }
    const unsigned T = s_prefix;  // key of the 512th-largest value
    for (int ki = mlo + tid; ki <= mhi; ki += 256) {
      if (fkey(sc[ki]) > T) sel[ki] = 1;
    }
    __syncthreads();
    if (tid == 0) {
      // ties at T: lowest index first (jax.lax.top_k stability)
      int r = (int)s_remaining;
      for (int ki = mlo; ki <= mhi && r > 0; ++ki) {
        if (fkey(sc[ki]) == T) { sel[ki] = 1; --r; }
      }
    }
    __syncthreads();
  }

  // ---- softmax over selected ----
  float lmax = -3.402823466e38f;
  for (int ki = tid; ki < nk; ki += 256)
    if (sel[ki]) lmax = fmaxf(lmax, sc[ki]);
  red[tid] = lmax;
  __syncthreads();
#pragma unroll
  for (int off = 128; off >= 1; off >>= 1) {
    if (tid < off) red[tid] = fmaxf(red[tid], red[tid + off]);
    __syncthreads();
  }
  const float maxv = red[0];
  __syncthreads();

  float lsum = 0.f;
  for (int ki = tid; ki < nk; ki += 256) {
    if (sel[ki]) {
      float e = expf(sc[ki] - maxv);
      sc[ki] = e;
      lsum += e;
    }
  }
  red[tid] = lsum;
  __syncthreads();
#pragma unroll
  for (int off = 128; off >= 1; off >>= 1) {
    if (tid < off) red[tid] += red[tid + off];
    __syncthreads();
  }
  const float sumv = red[0];
  __syncthreads();

  // ---- P @ V over selected keys (sel[ki] is wave-uniform) ----
  const int d = tid & (HD - 1);
  const int half = tid >> 7;
  float acc = 0.f;
  for (int ki = half; ki < nk; ki += 2) {
    if (sel[ki]) acc += sc[ki] * v[((size_t)ki * NKV + g) * HD + d];
  }
  pv[half][d] = acc;
  __syncthreads();
  if (tid < HD) {
    ao[((size_t)qi * NH + h) * HD + tid] = (pv[0][tid] + pv[1][tid]) / sumv;
  }
}

// ---------------------------------------------------------------------------
extern "C" void kernel_launch(void* const* d_in, const int* in_sizes, int n_in,
                              void* d_out, int out_size, void* d_ws, size_t ws_size,
                              hipStream_t stream) {
  const float* hidden = (const float*)d_in[0];   // [S][HID]
  const float* wq = (const float*)d_in[1];       // [HID][NH*HD]
  const float* wk = (const float*)d_in[2];       // [HID][NKV*HD]
  const float* wv = (const float*)d_in[3];       // [HID][NKV*HD]
  const float* wo = (const float*)d_in[4];       // [NH*HD][HID]
  float* out = (float*)d_out;                    // [S][HID]

  float* q    = (float*)d_ws;                       // S * NH*HD
  float* kbuf = q + (size_t)S_LEN * NH * HD;        // S * NKV*HD
  float* vbuf = kbuf + (size_t)S_LEN * NKV * HD;    // S * NKV*HD
  float* ao   = vbuf + (size_t)S_LEN * NKV * HD;    // S * NH*HD

  dim3 blk(256);
  gemm_f32<<<dim3((NH * HD) / BN, S_LEN / BM), blk, 0, stream>>>(hidden, wq, q, S_LEN, NH * HD, HID_N);
  gemm_f32<<<dim3((NKV * HD) / BN, S_LEN / BM), blk, 0, stream>>>(hidden, wk, kbuf, S_LEN, NKV * HD, HID_N);
  gemm_f32<<<dim3((NKV * HD) / BN, S_LEN / BM), blk, 0, stream>>>(hidden, wv, vbuf, S_LEN, NKV * HD, HID_N);
  rope_f32<<<(S_LEN * NH * 64) / 256, blk, 0, stream>>>(q, NH);
  rope_f32<<<(S_LEN * NKV * 64) / 256, blk, 0, stream>>>(kbuf, NKV);
  attn_kernel<<<dim3(S_LEN, NH), blk, 0, stream>>>(q, kbuf, vbuf, ao);
  gemm_f32<<<dim3(HID_N / BN, S_LEN / BM), blk, 0, stream>>>(ao, wo, out, S_LEN, HID_N, NH * HD);
}

// Round 2
// 7302.787 us; speedup vs baseline: 4.7812x; 4.7812x over previous
//
#include <hip/hip_runtime.h>
#include <math.h>

#define S_LEN 2048
#define HID_N 4096
#define NH 32
#define NKV 8
#define HD 128
#define INIT_N 128
#define RECENT_N 512
#define HEAVY_N 512

// ---------------- fp32 tiled GEMM: C[M][N] = A[M][K] @ B[K][N], row-major ----
#define BM 64
#define BN 64
#define BK 16

__global__ __launch_bounds__(256) void gemm_f32(const float* __restrict__ A,
                                                const float* __restrict__ B,
                                                float* __restrict__ C,
                                                int M, int N, int K) {
  __shared__ float As[BK][BM];   // transposed A tile: As[k][m]
  __shared__ float Bs[BK][BN];
  const int tid = threadIdx.x;
  const int tx = tid & 15;   // N direction
  const int ty = tid >> 4;   // M direction
  const int bm = blockIdx.y * BM;
  const int bn = blockIdx.x * BN;
  const int a_r = tid >> 2;          // 0..63
  const int a_c = (tid & 3) << 2;    // 0,4,8,12
  const int b_r = tid >> 4;          // 0..15
  const int b_c = (tid & 15) << 2;   // 0..60

  float acc[4][4] = {};
  for (int k0 = 0; k0 < K; k0 += BK) {
    float4 av = *(const float4*)(A + (size_t)(bm + a_r) * K + (k0 + a_c));
    float4 bv = *(const float4*)(B + (size_t)(k0 + b_r) * N + (bn + b_c));
    As[a_c + 0][a_r] = av.x;
    As[a_c + 1][a_r] = av.y;
    As[a_c + 2][a_r] = av.z;
    As[a_c + 3][a_r] = av.w;
    *(float4*)&Bs[b_r][b_c] = bv;
    __syncthreads();
#pragma unroll
    for (int kk = 0; kk < BK; ++kk) {
      float4 a = *(const float4*)&As[kk][ty << 2];
      float4 b = *(const float4*)&Bs[kk][tx << 2];
      float ar[4] = {a.x, a.y, a.z, a.w};
      float br[4] = {b.x, b.y, b.z, b.w};
#pragma unroll
      for (int i = 0; i < 4; ++i)
#pragma unroll
        for (int j = 0; j < 4; ++j) acc[i][j] = fmaf(ar[i], br[j], acc[i][j]);
    }
    __syncthreads();
  }
#pragma unroll
  for (int i = 0; i < 4; ++i) {
    float4 o = make_float4(acc[i][0], acc[i][1], acc[i][2], acc[i][3]);
    *(float4*)(C + (size_t)(bm + (ty << 2) + i) * N + bn + (tx << 2)) = o;
  }
}

// ---------------- RoPE in place: x is [S][nheads*HD], pairs (i, i+64) --------
__global__ __launch_bounds__(256) void rope_f32(float* __restrict__ x, int nheads) {
  int idx = blockIdx.x * 256 + threadIdx.x;
  int i = idx & 63;            // rotary pair index 0..63
  int rest = idx >> 6;
  int hh = rest % nheads;
  int s = rest / nheads;
  if (s >= S_LEN) return;
  float* p = x + ((size_t)s * nheads + hh) * HD;
  float inv = (float)(1.0 / pow(10000.0, (double)(2 * i) / 128.0));
  float ang = (float)s * inv;
  float c = cosf(ang);
  float sn = sinf(ang);
  float x1 = p[i];
  float x2 = p[i + 64];
  p[i] = x1 * c - x2 * sn;
  p[i + 64] = x2 * c + x1 * sn;
}

// ---------------- fused heavy-hitter attention, one block per (qi, head) -----
__device__ __forceinline__ unsigned fkey(float f) {
  // order-preserving float -> uint (larger float => larger uint)
  unsigned u = __float_as_uint(f);
  return (u & 0x80000000u) ? ~u : (u | 0x80000000u);
}

__global__ __launch_bounds__(256, 4) void attn_kernel(const float* __restrict__ q,
                                                      const float* __restrict__ k,
                                                      const float* __restrict__ v,
                                                      float* __restrict__ ao) {
  const int qi = blockIdx.x;
  const int h = blockIdx.y;
  const int g = h >> 2;            // NH/NKV = 4 -> kv head
  const int tid = threadIdx.x;
  const int lane = tid & 63;
  const int wid = tid >> 6;
  const int nk = qi + 1;

  __shared__ float qs[HD];
  __shared__ float sc[S_LEN];
  __shared__ unsigned char sel[S_LEN];
  __shared__ unsigned short idxl[S_LEN];
  __shared__ unsigned redu[4];
  __shared__ float redf[4];
  __shared__ float pv[2][HD];

  if (tid < HD) qs[tid] = q[((size_t)qi * NH + h) * HD + tid];
  __syncthreads();

  // ---- scores for causal keys, init base-mask ----
  for (int ki = tid; ki < nk; ki += 256) {
    const float4* kr = (const float4*)(k + ((size_t)ki * NKV + g) * HD);
    const float4* qr = (const float4*)qs;
    float dot = 0.f;
#pragma unroll 8
    for (int j = 0; j < HD / 4; ++j) {
      float4 a = qr[j];
      float4 b = kr[j];
      dot += a.x * b.x + a.y * b.y + a.z * b.z + a.w * b.w;
    }
    sc[ki] = dot * 0.08838834764831845f;  // 1/sqrt(128)
    bool middle = (ki >= INIT_N) && (ki + RECENT_N <= qi);
    sel[ki] = middle ? 0 : 1;  // base = causal & !middle
  }
  __syncthreads();

  // ---- heavy-hitter selection over middle window [INIT, qi-RECENT] ----
  const int mlo = INIT_N;
  const int mhi = qi - RECENT_N;
  const int m = mhi - mlo + 1;
  if (m > 0 && m <= HEAVY_N) {
    for (int ki = mlo + tid; ki <= mhi; ki += 256) sel[ki] = 1;
    __syncthreads();
  } else if (m > HEAVY_N) {
    // cache this thread's keys in registers (m <= 1408 -> <= 6 per thread)
    unsigned myk[6];
    int myn = 0;
    for (int ki = mlo + tid; ki <= mhi; ki += 256) myk[myn++] = fkey(sc[ki]);

    // bitwise binary search for T = key of HEAVY-th largest (exact, no atomics)
    unsigned prefix = 0;
    unsigned rem = HEAVY_N;   // uniform across all threads
#pragma unroll 1
    for (int bit = 31; bit >= 0; --bit) {
      const unsigned target = (prefix >> bit) | 1u;
      unsigned cnt = 0;
#pragma unroll
      for (int i = 0; i < 6; ++i)
        if (i < myn) cnt += ((myk[i] >> bit) == target) ? 1u : 0u;
#pragma unroll
      for (int off = 32; off > 0; off >>= 1) cnt += __shfl_xor((int)cnt, off, 64);
      __syncthreads();
      if (lane == 0) redu[wid] = cnt;
      __syncthreads();
      unsigned c1 = redu[0] + redu[1] + redu[2] + redu[3];
      if (c1 >= rem) prefix |= (1u << bit);
      else rem -= c1;
    }
    const unsigned T = prefix;

    // mark strictly-greater keys
    {
      int i = 0;
      for (int ki = mlo + tid; ki <= mhi; ki += 256, ++i)
        if (myk[i] > T) sel[ki] = 1;
    }
    __syncthreads();

    // tie-fill: first `rem` elements with key == T, ascending index (top_k stability)
    int base = 0;
#pragma unroll 1
    for (int c0 = mlo; c0 <= mhi; c0 += 256) {
      const int ki = c0 + tid;
      const bool match = (ki <= mhi) && (fkey(sc[ki]) == T);
      unsigned long long mb = __ballot(match);
      int lr = __popcll(mb & ((1ull << lane) - 1ull));
      __syncthreads();
      if (lane == 0) redu[wid] = (unsigned)__popcll(mb);
      __syncthreads();
      int pw = 0, tot = 0;
#pragma unroll
      for (int w = 0; w < 4; ++w) {
        int c = (int)redu[w];
        if (w < wid) pw += c;
        tot += c;
      }
      if (match && (base + pw + lr) < (int)rem) sel[ki] = 1;
      base += tot;
    }
    __syncthreads();
  }

  // ---- stable stream-compaction of selected indices into idxl ----
  int nsel = 0;
#pragma unroll 1
  for (int c0 = 0; c0 < nk; c0 += 256) {
    const int ki = c0 + tid;
    const bool p = (ki < nk) && sel[ki];
    unsigned long long mb = __ballot(p);
    int lr = __popcll(mb & ((1ull << lane) - 1ull));
    __syncthreads();
    if (lane == 0) redu[wid] = (unsigned)__popcll(mb);
    __syncthreads();
    int pw = 0, tot = 0;
#pragma unroll
    for (int w = 0; w < 4; ++w) {
      int c = (int)redu[w];
      if (w < wid) pw += c;
      tot += c;
    }
    if (p) idxl[nsel + pw + lr] = (unsigned short)ki;
    nsel += tot;
  }
  __syncthreads();

  // ---- softmax over compacted list ----
  float lmax = -3.402823466e38f;
  for (int j = tid; j < nsel; j += 256) lmax = fmaxf(lmax, sc[idxl[j]]);
#pragma unroll
  for (int off = 32; off > 0; off >>= 1) lmax = fmaxf(lmax, __shfl_xor(lmax, off, 64));
  if (lane == 0) redf[wid] = lmax;
  __syncthreads();
  const float maxv = fmaxf(fmaxf(redf[0], redf[1]), fmaxf(redf[2], redf[3]));
  __syncthreads();

  float lsum = 0.f;
  for (int j = tid; j < nsel; j += 256) {
    const int ki = idxl[j];
    float e = __expf(sc[ki] - maxv);
    sc[ki] = e;
    lsum += e;
  }
#pragma unroll
  for (int off = 32; off > 0; off >>= 1) lsum += __shfl_xor(lsum, off, 64);
  if (lane == 0) redf[wid] = lsum;
  __syncthreads();
  const float sumv = redf[0] + redf[1] + redf[2] + redf[3];
  __syncthreads();

  // ---- P @ V over compacted list, unrolled x4 for loads in flight ----
  const int d = tid & (HD - 1);
  const int half = tid >> 7;
  const float* __restrict__ vg = v + (size_t)g * HD + d;
  float acc = 0.f;
  int j = half;
  for (; j + 6 < nsel; j += 8) {
    const int k0 = idxl[j], k1 = idxl[j + 2], k2 = idxl[j + 4], k3 = idxl[j + 6];
    const float p0 = sc[k0], p1 = sc[k1], p2 = sc[k2], p3 = sc[k3];
    const float v0 = vg[(size_t)k0 * (NKV * HD)];
    const float v1 = vg[(size_t)k1 * (NKV * HD)];
    const float v2 = vg[(size_t)k2 * (NKV * HD)];
    const float v3 = vg[(size_t)k3 * (NKV * HD)];
    acc += p0 * v0 + p1 * v1 + p2 * v2 + p3 * v3;
  }
  for (; j < nsel; j += 2) {
    const int k0 = idxl[j];
    acc += sc[k0] * vg[(size_t)k0 * (NKV * HD)];
  }
  pv[half][d] = acc;
  __syncthreads();
  if (tid < HD) {
    ao[((size_t)qi * NH + h) * HD + tid] = (pv[0][tid] + pv[1][tid]) / sumv;
  }
}

// ---------------------------------------------------------------------------
extern "C" void kernel_launch(void* const* d_in, const int* in_sizes, int n_in,
                              void* d_out, int out_size, void* d_ws, size_t ws_size,
                              hipStream_t stream) {
  const float* hidden = (const float*)d_in[0];   // [S][HID]
  const float* wq = (const float*)d_in[1];       // [HID][NH*HD]
  const float* wk = (const float*)d_in[2];       // [HID][NKV*HD]
  const float* wv = (const float*)d_in[3];       // [HID][NKV*HD]
  const float* wo = (const float*)d_in[4];       // [NH*HD][HID]
  float* out = (float*)d_out;                    // [S][HID]

  float* q    = (float*)d_ws;                       // S * NH*HD
  float* kbuf = q + (size_t)S_LEN * NH * HD;        // S * NKV*HD
  float* vbuf = kbuf + (size_t)S_LEN * NKV * HD;    // S * NKV*HD
  float* ao   = vbuf + (size_t)S_LEN * NKV * HD;    // S * NH*HD

  dim3 blk(256);
  gemm_f32<<<dim3((NH * HD) / BN, S_LEN / BM), blk, 0, stream>>>(hidden, wq, q, S_LEN, NH * HD, HID_N);
  gemm_f32<<<dim3((NKV * HD) / BN, S_LEN / BM), blk, 0, stream>>>(hidden, wk, kbuf, S_LEN, NKV * HD, HID_N);
  gemm_f32<<<dim3((NKV * HD) / BN, S_LEN / BM), blk, 0, stream>>>(hidden, wv, vbuf, S_LEN, NKV * HD, HID_N);
  rope_f32<<<(S_LEN * NH * 64) / 256, blk, 0, stream>>>(q, NH);
  rope_f32<<<(S_LEN * NKV * 64) / 256, blk, 0, stream>>>(kbuf, NKV);
  attn_kernel<<<dim3(S_LEN, NH), blk, 0, stream>>>(q, kbuf, vbuf, ao);
  gemm_f32<<<dim3(HID_N / BN, S_LEN / BM), blk, 0, stream>>>(ao, wo, out, S_LEN, HID_N, NH * HD);
}

// Round 3
// 4217.506 us; speedup vs baseline: 8.2788x; 1.7315x over previous
//
#include <hip/hip_runtime.h>
#include <math.h>

#define S_LEN 2048
#define HID_N 4096
#define NH 32
#define NKV 8
#define HD 128
#define INIT_N 128
#define RECENT_N 512
#define HEAVY_N 512
#define TQ 4
#define SCALE_QK 0.08838834764831845f

// ---------------- fp32 tiled GEMM: C[M][N] = A[M][K] @ B[K][N], row-major ----
#define BM 64
#define BN 64
#define BK 16

__global__ __launch_bounds__(256) void gemm_f32(const float* __restrict__ A,
                                                const float* __restrict__ B,
                                                float* __restrict__ C,
                                                int M, int N, int K) {
  __shared__ float As[BK][BM];
  __shared__ float Bs[BK][BN];
  const int tid = threadIdx.x;
  const int tx = tid & 15;
  const int ty = tid >> 4;
  const int bm = blockIdx.y * BM;
  const int bn = blockIdx.x * BN;
  const int a_r = tid >> 2;
  const int a_c = (tid & 3) << 2;
  const int b_r = tid >> 4;
  const int b_c = (tid & 15) << 2;

  float acc[4][4] = {};
  for (int k0 = 0; k0 < K; k0 += BK) {
    float4 av = *(const float4*)(A + (size_t)(bm + a_r) * K + (k0 + a_c));
    float4 bv = *(const float4*)(B + (size_t)(k0 + b_r) * N + (bn + b_c));
    As[a_c + 0][a_r] = av.x;
    As[a_c + 1][a_r] = av.y;
    As[a_c + 2][a_r] = av.z;
    As[a_c + 3][a_r] = av.w;
    *(float4*)&Bs[b_r][b_c] = bv;
    __syncthreads();
#pragma unroll
    for (int kk = 0; kk < BK; ++kk) {
      float4 a = *(const float4*)&As[kk][ty << 2];
      float4 b = *(const float4*)&Bs[kk][tx << 2];
      float ar[4] = {a.x, a.y, a.z, a.w};
      float br[4] = {b.x, b.y, b.z, b.w};
#pragma unroll
      for (int i = 0; i < 4; ++i)
#pragma unroll
        for (int j = 0; j < 4; ++j) acc[i][j] = fmaf(ar[i], br[j], acc[i][j]);
    }
    __syncthreads();
  }
#pragma unroll
  for (int i = 0; i < 4; ++i) {
    float4 o = make_float4(acc[i][0], acc[i][1], acc[i][2], acc[i][3]);
    *(float4*)(C + (size_t)(bm + (ty << 2) + i) * N + bn + (tx << 2)) = o;
  }
}

// Same GEMM but stores C transposed: CT[N][M] (used for k-projection -> kT).
__global__ __launch_bounds__(256) void gemm_f32_tn(const float* __restrict__ A,
                                                   const float* __restrict__ B,
                                                   float* __restrict__ CT,
                                                   int M, int N, int K) {
  __shared__ float As[BK][BM];
  __shared__ float Bs[BK][BN];
  const int tid = threadIdx.x;
  const int tx = tid & 15;
  const int ty = tid >> 4;
  const int bm = blockIdx.y * BM;
  const int bn = blockIdx.x * BN;
  const int a_r = tid >> 2;
  const int a_c = (tid & 3) << 2;
  const int b_r = tid >> 4;
  const int b_c = (tid & 15) << 2;

  float acc[4][4] = {};
  for (int k0 = 0; k0 < K; k0 += BK) {
    float4 av = *(const float4*)(A + (size_t)(bm + a_r) * K + (k0 + a_c));
    float4 bv = *(const float4*)(B + (size_t)(k0 + b_r) * N + (bn + b_c));
    As[a_c + 0][a_r] = av.x;
    As[a_c + 1][a_r] = av.y;
    As[a_c + 2][a_r] = av.z;
    As[a_c + 3][a_r] = av.w;
    *(float4*)&Bs[b_r][b_c] = bv;
    __syncthreads();
#pragma unroll
    for (int kk = 0; kk < BK; ++kk) {
      float4 a = *(const float4*)&As[kk][ty << 2];
      float4 b = *(const float4*)&Bs[kk][tx << 2];
      float ar[4] = {a.x, a.y, a.z, a.w};
      float br[4] = {b.x, b.y, b.z, b.w};
#pragma unroll
      for (int i = 0; i < 4; ++i)
#pragma unroll
        for (int j = 0; j < 4; ++j) acc[i][j] = fmaf(ar[i], br[j], acc[i][j]);
    }
    __syncthreads();
  }
#pragma unroll
  for (int j = 0; j < 4; ++j) {
    float4 o = make_float4(acc[0][j], acc[1][j], acc[2][j], acc[3][j]);
    *(float4*)(CT + (size_t)(bn + (tx << 2) + j) * M + bm + (ty << 2)) = o;
  }
}

// ---------------- RoPE in place on [S][nheads*HD] (q path) ------------------
__global__ __launch_bounds__(256) void rope_f32(float* __restrict__ x, int nheads) {
  int idx = blockIdx.x * 256 + threadIdx.x;
  int i = idx & 63;
  int rest = idx >> 6;
  int hh = rest % nheads;
  int s = rest / nheads;
  if (s >= S_LEN) return;
  float* p = x + ((size_t)s * nheads + hh) * HD;
  float inv = (float)(1.0 / pow(10000.0, (double)(2 * i) / 128.0));
  float ang = (float)s * inv;
  float c = cosf(ang);
  float sn = sinf(ang);
  float x1 = p[i];
  float x2 = p[i + 64];
  p[i] = x1 * c - x2 * sn;
  p[i + 64] = x2 * c + x1 * sn;
}

// ---------------- RoPE in place on kT[g][d][s] layout -----------------------
__global__ __launch_bounds__(256) void rope_kT(float* __restrict__ kT) {
  int idx = blockIdx.x * 256 + threadIdx.x;   // 262144 total
  int s4 = (idx & 511) << 2;
  int rest = idx >> 9;
  int d = rest & 63;
  int g = rest >> 6;
  float inv = (float)(1.0 / pow(10000.0, (double)(2 * d) / 128.0));
  float* p1 = kT + ((size_t)g * HD + d) * S_LEN + s4;
  float* p2 = p1 + (size_t)64 * S_LEN;
  float4 a = *(float4*)p1;
  float4 b = *(float4*)p2;
  float4 oa, ob;
  {
    float ang = (float)(s4 + 0) * inv, c = cosf(ang), sn = sinf(ang);
    oa.x = a.x * c - b.x * sn; ob.x = b.x * c + a.x * sn;
  }
  {
    float ang = (float)(s4 + 1) * inv, c = cosf(ang), sn = sinf(ang);
    oa.y = a.y * c - b.y * sn; ob.y = b.y * c + a.y * sn;
  }
  {
    float ang = (float)(s4 + 2) * inv, c = cosf(ang), sn = sinf(ang);
    oa.z = a.z * c - b.z * sn; ob.z = b.z * c + a.z * sn;
  }
  {
    float ang = (float)(s4 + 3) * inv, c = cosf(ang), sn = sinf(ang);
    oa.w = a.w * c - b.w * sn; ob.w = b.w * c + a.w * sn;
  }
  *(float4*)p1 = oa;
  *(float4*)p2 = ob;
}

// ---------------- fused heavy-hitter attention, TQ=4 rows per block ----------
__device__ __forceinline__ unsigned fkey(float f) {
  unsigned u = __float_as_uint(f);
  return (u & 0x80000000u) ? ~u : (u | 0x80000000u);
}

__global__ __launch_bounds__(256, 4) void attn_kernel(const float* __restrict__ q,
                                                      const float* __restrict__ kT,
                                                      const float* __restrict__ v,
                                                      float* __restrict__ ao) {
  const int qi0 = blockIdx.x * TQ;
  const int h = blockIdx.y;
  const int g = h >> 2;
  const int tid = threadIdx.x;
  const int lane = tid & 63;
  const int wid = tid >> 6;
  const int nkm = qi0 + TQ;       // keys 0..qi0+TQ-1 cover all rows' causal sets

  __shared__ float sc[TQ][S_LEN];     // scores -> p values; reused as pvred at end
  __shared__ float qsm[HD][TQ];       // interleaved q rows
  __shared__ float sumv[TQ];

  // load 4 q rows into LDS interleaved
#pragma unroll
  for (int it = 0; it < 2; ++it) {
    int r = it * 2 + (tid >> 7);
    int d = tid & 127;
    qsm[d][r] = q[((size_t)(qi0 + r) * NH + h) * HD + d];
  }
  __syncthreads();

  // ---- score phase: lanes across ki (coalesced kT loads), 4 dots per thread
  for (int c0 = 0; c0 < nkm; c0 += 256) {
    int ki = c0 + tid;
    if (ki < nkm) {
      const float* kp = kT + (size_t)g * (HD * S_LEN) + ki;
      float d0 = 0.f, d1 = 0.f, d2 = 0.f, d3 = 0.f;
#pragma unroll 8
      for (int dd = 0; dd < HD; ++dd) {
        float kv = kp[(size_t)dd * S_LEN];
        float4 qv = *(const float4*)&qsm[dd][0];
        d0 = fmaf(qv.x, kv, d0);
        d1 = fmaf(qv.y, kv, d1);
        d2 = fmaf(qv.z, kv, d2);
        d3 = fmaf(qv.w, kv, d3);
      }
      sc[0][ki] = d0 * SCALE_QK;
      sc[1][ki] = d1 * SCALE_QK;
      sc[2][ki] = d2 * SCALE_QK;
      sc[3][ki] = d3 * SCALE_QK;
    }
  }
  __syncthreads();

  // ---- per-row selection + softmax: wave r owns row r (no block syncs) ----
  {
    const int r = wid;
    const int qi = qi0 + r;
    const int mhi = qi - RECENT_N;
    const int m = mhi - INIT_N + 1;
    const bool need = (m > HEAVY_N);
    unsigned T = 0xFFFFFFFFu, rem = 0;
    if (need) {
      unsigned myk[22];
#pragma unroll
      for (int j = 0; j < 22; ++j) {
        int off = lane + j * 64;
        myk[j] = (off < m) ? fkey(sc[r][INIT_N + off]) : 0u;
      }
      unsigned prefix = 0, rm = HEAVY_N;
#pragma unroll 1
      for (int bit = 31; bit >= 0; --bit) {
        unsigned target = (prefix >> bit) | 1u;
        unsigned cnt = 0;
#pragma unroll
        for (int j = 0; j < 22; ++j) cnt += ((myk[j] >> bit) == target) ? 1u : 0u;
#pragma unroll
        for (int off = 32; off; off >>= 1) cnt += (unsigned)__shfl_xor((int)cnt, off, 64);
        if (cnt >= rm) prefix |= (1u << bit);
        else rm -= cnt;
      }
      T = prefix;
      rem = rm;
    }
    const unsigned long long lmlt = (1ull << lane) - 1ull;

    // pass A: max over selected
    float mx = -3.402823466e38f;
    unsigned cum = 0;
#pragma unroll 1
    for (int c0 = 0; c0 <= qi; c0 += 64) {
      int ki = c0 + lane;
      bool incau = ki <= qi;
      float s = sc[r][ki];
      bool selg;
      if (!need) {
        selg = incau;
      } else {
        bool mid = incau && (ki >= INIT_N) && (ki <= mhi);
        unsigned kk = fkey(s);
        unsigned long long eq = __ballot(mid && (kk == T));
        bool hv = mid && ((kk > T) ||
                          ((kk == T) && (cum + (unsigned)__popcll(eq & lmlt) < rem)));
        cum += (unsigned)__popcll(eq);
        selg = incau && (!mid || hv);
      }
      if (selg) mx = fmaxf(mx, s);
    }
#pragma unroll
    for (int off = 32; off; off >>= 1) mx = fmaxf(mx, __shfl_xor(mx, off, 64));

    // pass B: exp/sum; write p (0 for unselected) for all ki < nkm
    float sum = 0.f;
    cum = 0;
#pragma unroll 1
    for (int c0 = 0; c0 < nkm; c0 += 64) {
      int ki = c0 + lane;
      bool incau = ki <= qi;
      float s = sc[r][ki];
      bool selg;
      if (!need) {
        selg = incau;
      } else {
        bool mid = incau && (ki >= INIT_N) && (ki <= mhi);
        unsigned kk = fkey(s);
        unsigned long long eq = __ballot(mid && (kk == T));
        bool hv = mid && ((kk > T) ||
                          ((kk == T) && (cum + (unsigned)__popcll(eq & lmlt) < rem)));
        cum += (unsigned)__popcll(eq);
        selg = incau && (!mid || hv);
      }
      float e = selg ? __expf(s - mx) : 0.f;
      sum += e;
      if (ki < nkm) sc[r][ki] = e;
    }
#pragma unroll
    for (int off = 32; off; off >>= 1) sum += __shfl_xor(sum, off, 64);
    if (lane == 0) sumv[r] = sum;
  }
  __syncthreads();

  // ---- P @ V: wave-per-key, coalesced float2 v loads, 4 rows at once ----
  const int d2 = lane << 1;
  const float* vb = v + (size_t)g * HD + d2;
  float a00 = 0.f, a01 = 0.f, a10 = 0.f, a11 = 0.f;
  float a20 = 0.f, a21 = 0.f, a30 = 0.f, a31 = 0.f;
#pragma unroll 2
  for (int ki = wid; ki < nkm; ki += 4) {
    float p0 = sc[0][ki], p1 = sc[1][ki], p2 = sc[2][ki], p3 = sc[3][ki];
    if ((p0 != 0.f) || (p1 != 0.f) || (p2 != 0.f) || (p3 != 0.f)) {
      float2 v2 = *(const float2*)(vb + (size_t)ki * (NKV * HD));
      a00 = fmaf(p0, v2.x, a00); a01 = fmaf(p0, v2.y, a01);
      a10 = fmaf(p1, v2.x, a10); a11 = fmaf(p1, v2.y, a11);
      a20 = fmaf(p2, v2.x, a20); a21 = fmaf(p2, v2.y, a21);
      a30 = fmaf(p3, v2.x, a30); a31 = fmaf(p3, v2.y, a31);
    }
  }
  __syncthreads();   // done reading sc as p-values

  // overlay partial sums into sc region: pvred[w][r][d] (4*4*128 floats)
  float* pvred = &sc[0][0];
  {
    const int base = (wid * 4) << 7;
    *(float2*)&pvred[base + (0 << 7) + d2] = make_float2(a00, a01);
    *(float2*)&pvred[base + (1 << 7) + d2] = make_float2(a10, a11);
    *(float2*)&pvred[base + (2 << 7) + d2] = make_float2(a20, a21);
    *(float2*)&pvred[base + (3 << 7) + d2] = make_float2(a30, a31);
  }
  __syncthreads();

#pragma unroll
  for (int it = 0; it < 2; ++it) {
    int o = it * 256 + tid;
    int r = o >> 7;
    int d = o & 127;
    float vs = pvred[((0 * 4 + r) << 7) + d] + pvred[((1 * 4 + r) << 7) + d] +
               pvred[((2 * 4 + r) << 7) + d] + pvred[((3 * 4 + r) << 7) + d];
    ao[((size_t)(qi0 + r) * NH + h) * HD + d] = vs / sumv[r];
  }
}

// ---------------------------------------------------------------------------
extern "C" void kernel_launch(void* const* d_in, const int* in_sizes, int n_in,
                              void* d_out, int out_size, void* d_ws, size_t ws_size,
                              hipStream_t stream) {
  const float* hidden = (const float*)d_in[0];
  const float* wq = (const float*)d_in[1];
  const float* wk = (const float*)d_in[2];
  const float* wv = (const float*)d_in[3];
  const float* wo = (const float*)d_in[4];
  float* out = (float*)d_out;

  float* q    = (float*)d_ws;                       // S * NH*HD       (8M floats)
  float* kT   = q + (size_t)S_LEN * NH * HD;        // NKV*HD * S      (2M floats)
  float* vbuf = kT + (size_t)NKV * HD * S_LEN;      // S * NKV*HD      (2M floats)
  float* ao   = vbuf + (size_t)S_LEN * NKV * HD;    // S * NH*HD       (8M floats)

  dim3 blk(256);
  gemm_f32<<<dim3((NH * HD) / BN, S_LEN / BM), blk, 0, stream>>>(hidden, wq, q, S_LEN, NH * HD, HID_N);
  gemm_f32_tn<<<dim3((NKV * HD) / BN, S_LEN / BM), blk, 0, stream>>>(hidden, wk, kT, S_LEN, NKV * HD, HID_N);
  gemm_f32<<<dim3((NKV * HD) / BN, S_LEN / BM), blk, 0, stream>>>(hidden, wv, vbuf, S_LEN, NKV * HD, HID_N);
  rope_f32<<<(S_LEN * NH * 64) / 256, blk, 0, stream>>>(q, NH);
  rope_kT<<<(NKV * 64 * (S_LEN / 4)) / 256, blk, 0, stream>>>(kT);
  attn_kernel<<<dim3(S_LEN / TQ, NH), blk, 0, stream>>>(q, kT, vbuf, ao);
  gemm_f32<<<dim3(HID_N / BN, S_LEN / BM), blk, 0, stream>>>(ao, wo, out, S_LEN, HID_N, NH * HD);
}

// Round 4
// 2147.383 us; speedup vs baseline: 16.2597x; 1.9640x over previous
//
#include <hip/hip_runtime.h>
#include <math.h>

#define S_LEN 2048
#define HID_N 4096
#define NH 32
#define NKV 8
#define HD 128
#define INIT_N 128
#define RECENT_N 512
#define HEAVY_N 512
#define TQ 4
#define SCALE_QK 0.08838834764831845f

typedef __attribute__((ext_vector_type(8))) short short8;
typedef __attribute__((ext_vector_type(4))) float float4v;

__device__ __forceinline__ unsigned short f2bf(float f) {
  unsigned u = __float_as_uint(f);
  unsigned r = (u + 0x7FFFu + ((u >> 16) & 1u)) >> 16;  // RNE (inputs finite)
  return (unsigned short)r;
}

__device__ __forceinline__ void gld_lds16(const unsigned short* g, unsigned short* l) {
  __builtin_amdgcn_global_load_lds(
      (const __attribute__((address_space(1))) unsigned int*)g,
      (__attribute__((address_space(3))) unsigned int*)l, 16, 0, 0);
}

// ---------------- elementwise cast fp32 -> bf16, 8 per thread ----------------
__global__ __launch_bounds__(256) void cast_bf16x8(const float* __restrict__ x,
                                                   unsigned short* __restrict__ y, int n) {
  int i = (blockIdx.x * 256 + threadIdx.x) << 3;
  if (i >= n) return;
  float4 a = *(const float4*)(x + i);
  float4 b = *(const float4*)(x + i + 4);
  union { unsigned short u[8]; short8 v; } o;
  o.u[0] = f2bf(a.x); o.u[1] = f2bf(a.y); o.u[2] = f2bf(a.z); o.u[3] = f2bf(a.w);
  o.u[4] = f2bf(b.x); o.u[5] = f2bf(b.y); o.u[6] = f2bf(b.z); o.u[7] = f2bf(b.w);
  *(short8*)(y + i) = o.v;
}

// ---------------- transpose + cast: w[R][C] fp32 -> wt[C][R] bf16 ------------
__global__ __launch_bounds__(256) void transpose_cast(const float* __restrict__ w,
                                                      unsigned short* __restrict__ wt,
                                                      int R, int C) {
  __shared__ unsigned short t[64][65];
  const int c0 = blockIdx.x * 64;
  const int r0 = blockIdx.y * 64;
  const int tx = threadIdx.x & 63;
  const int ty = threadIdx.x >> 6;
#pragma unroll
  for (int i = 0; i < 16; ++i)
    t[ty + 4 * i][tx] = f2bf(w[(size_t)(r0 + ty + 4 * i) * C + c0 + tx]);
  __syncthreads();
#pragma unroll
  for (int i = 0; i < 16; ++i)
    wt[(size_t)(c0 + ty + 4 * i) * R + r0 + tx] = t[tx][ty + 4 * i];
}

// ---------------- bf16 MFMA GEMM (m97 pattern): C = A[M][K] @ BT[N][K]^T -----
// 128x128 tile, 4 waves 2x2, 16x16x32 bf16 MFMA, BK=32, global_load_lds x16.
__global__ __launch_bounds__(256) void gemm_bf16(const unsigned short* __restrict__ A,
                                                 const unsigned short* __restrict__ BT,
                                                 float* __restrict__ C,
                                                 int M, int N, int K) {
  __shared__ __align__(16) unsigned short As[128 * 32];
  __shared__ __align__(16) unsigned short Bs[128 * 32];
  const int tid = threadIdx.x;
  const int lane = tid & 63;
  const int wid = tid >> 6;
  const int m0 = blockIdx.y * 128;
  const int n0 = blockIdx.x * 128;
  const int wm = (wid & 1) * 64;
  const int wn = (wid >> 1) * 64;
  const int col = lane & 15;
  const int quad = lane >> 4;

  float4v acc[4][4] = {};

  const int crow = tid >> 2;              // chunk row for staging (tid-based)
  const int ckc = (tid & 3) << 3;         // k offset in elements (0,8,16,24)

  for (int k0 = 0; k0 < K; k0 += 32) {
#pragma unroll
    for (int i = 0; i < 2; ++i) {
      // chunk id c = i*256 + tid ; row = c>>2 = i*64 + crow ; k = ckc
      const int row = i * 64 + crow;
      unsigned short* la = &As[(i * 256 + wid * 64) << 3];
      unsigned short* lb = &Bs[(i * 256 + wid * 64) << 3];
      gld_lds16(A + (size_t)(m0 + row) * K + k0 + ckc, la);
      gld_lds16(BT + (size_t)(n0 + row) * K + k0 + ckc, lb);
    }
    __syncthreads();

    short8 af[4], bf[4];
#pragma unroll
    for (int i = 0; i < 4; ++i) {
      af[i] = *(const short8*)&As[((wm + 16 * i + col) << 5) + (quad << 3)];
      bf[i] = *(const short8*)&Bs[((wn + 16 * i + col) << 5) + (quad << 3)];
    }
#pragma unroll
    for (int i = 0; i < 4; ++i)
#pragma unroll
      for (int j = 0; j < 4; ++j)
        acc[i][j] = __builtin_amdgcn_mfma_f32_16x16x32_bf16(af[i], bf[j], acc[i][j], 0, 0, 0);
    __syncthreads();
  }

#pragma unroll
  for (int i = 0; i < 4; ++i)
#pragma unroll
    for (int j = 0; j < 4; ++j) {
      size_t base = (size_t)(m0 + wm + 16 * i + quad * 4) * N + n0 + wn + 16 * j + col;
      C[base] = acc[i][j][0];
      C[base + N] = acc[i][j][1];
      C[base + 2 * (size_t)N] = acc[i][j][2];
      C[base + 3 * (size_t)N] = acc[i][j][3];
    }
}

// ---------------- RoPE in place on [S][nheads*HD] (q path) ------------------
__global__ __launch_bounds__(256) void rope_f32(float* __restrict__ x, int nheads) {
  int idx = blockIdx.x * 256 + threadIdx.x;
  int i = idx & 63;
  int rest = idx >> 6;
  int hh = rest % nheads;
  int s = rest / nheads;
  if (s >= S_LEN) return;
  float* p = x + ((size_t)s * nheads + hh) * HD;
  float inv = (float)(1.0 / pow(10000.0, (double)(2 * i) / 128.0));
  float ang = (float)s * inv;
  float c = cosf(ang);
  float sn = sinf(ang);
  float x1 = p[i];
  float x2 = p[i + 64];
  p[i] = x1 * c - x2 * sn;
  p[i + 64] = x2 * c + x1 * sn;
}

// ---------------- transpose + RoPE: k[S][NKV*HD] -> kT[g][d][s] --------------
__global__ __launch_bounds__(256) void transpose_rope_k(const float* __restrict__ kin,
                                                        float* __restrict__ kT) {
  __shared__ float t1[64][65];
  __shared__ float t2[64][65];
  const int s0 = blockIdx.x * 64;
  const int g = blockIdx.y;
  const int tx = threadIdx.x & 63;
  const int ty = threadIdx.x >> 6;
  float inv = (float)(1.0 / pow(10000.0, (double)(2 * tx) / 128.0));
#pragma unroll
  for (int i = 0; i < 16; ++i) {
    int sl = ty + 4 * i;
    int s = s0 + sl;
    float a = kin[(size_t)s * (NKV * HD) + g * HD + tx];
    float b = kin[(size_t)s * (NKV * HD) + g * HD + 64 + tx];
    float ang = (float)s * inv;
    float c = cosf(ang), sn = sinf(ang);
    t1[sl][tx] = a * c - b * sn;
    t2[sl][tx] = b * c + a * sn;
  }
  __syncthreads();
#pragma unroll
  for (int i = 0; i < 16; ++i) {
    int d = ty + 4 * i;
    kT[((size_t)g * HD + d) * S_LEN + s0 + tx] = t1[tx][d];
    kT[((size_t)g * HD + 64 + d) * S_LEN + s0 + tx] = t2[tx][d];
  }
}

// ---------------- fused heavy-hitter attention, TQ=4 rows per block ----------
__device__ __forceinline__ unsigned fkey(float f) {
  unsigned u = __float_as_uint(f);
  return (u & 0x80000000u) ? ~u : (u | 0x80000000u);
}

__global__ __launch_bounds__(256, 4) void attn_kernel(const float* __restrict__ q,
                                                      const float* __restrict__ kT,
                                                      const float* __restrict__ v,
                                                      float* __restrict__ ao) {
  const int qi0 = blockIdx.x * TQ;
  const int h = blockIdx.y;
  const int g = h >> 2;
  const int tid = threadIdx.x;
  const int lane = tid & 63;
  const int wid = tid >> 6;
  const int nkm = qi0 + TQ;

  __shared__ float sc[TQ][S_LEN];
  __shared__ float qsm[HD][TQ];
  __shared__ float sumv[TQ];

#pragma unroll
  for (int it = 0; it < 2; ++it) {
    int r = it * 2 + (tid >> 7);
    int d = tid & 127;
    qsm[d][r] = q[((size_t)(qi0 + r) * NH + h) * HD + d];
  }
  __syncthreads();

  for (int c0 = 0; c0 < nkm; c0 += 256) {
    int ki = c0 + tid;
    if (ki < nkm) {
      const float* kp = kT + (size_t)g * (HD * S_LEN) + ki;
      float d0 = 0.f, d1 = 0.f, d2 = 0.f, d3 = 0.f;
#pragma unroll 8
      for (int dd = 0; dd < HD; ++dd) {
        float kv = kp[(size_t)dd * S_LEN];
        float4 qv = *(const float4*)&qsm[dd][0];
        d0 = fmaf(qv.x, kv, d0);
        d1 = fmaf(qv.y, kv, d1);
        d2 = fmaf(qv.z, kv, d2);
        d3 = fmaf(qv.w, kv, d3);
      }
      sc[0][ki] = d0 * SCALE_QK;
      sc[1][ki] = d1 * SCALE_QK;
      sc[2][ki] = d2 * SCALE_QK;
      sc[3][ki] = d3 * SCALE_QK;
    }
  }
  __syncthreads();

  {
    const int r = wid;
    const int qi = qi0 + r;
    const int mhi = qi - RECENT_N;
    const int m = mhi - INIT_N + 1;
    const bool need = (m > HEAVY_N);
    unsigned T = 0xFFFFFFFFu, rem = 0;
    if (need) {
      unsigned myk[22];
#pragma unroll
      for (int j = 0; j < 22; ++j) {
        int off = lane + j * 64;
        myk[j] = (off < m) ? fkey(sc[r][INIT_N + off]) : 0u;
      }
      unsigned prefix = 0, rm = HEAVY_N;
#pragma unroll 1
      for (int bit = 31; bit >= 0; --bit) {
        unsigned target = (prefix >> bit) | 1u;
        unsigned cnt = 0;
#pragma unroll
        for (int j = 0; j < 22; ++j) cnt += ((myk[j] >> bit) == target) ? 1u : 0u;
#pragma unroll
        for (int off = 32; off; off >>= 1) cnt += (unsigned)__shfl_xor((int)cnt, off, 64);
        if (cnt >= rm) prefix |= (1u << bit);
        else rm -= cnt;
      }
      T = prefix;
      rem = rm;
    }
    const unsigned long long lmlt = (1ull << lane) - 1ull;

    float mx = -3.402823466e38f;
    unsigned cum = 0;
#pragma unroll 1
    for (int c0 = 0; c0 <= qi; c0 += 64) {
      int ki = c0 + lane;
      bool incau = ki <= qi;
      float s = sc[r][ki];
      bool selg;
      if (!need) {
        selg = incau;
      } else {
        bool mid = incau && (ki >= INIT_N) && (ki <= mhi);
        unsigned kk = fkey(s);
        unsigned long long eq = __ballot(mid && (kk == T));
        bool hv = mid && ((kk > T) ||
                          ((kk == T) && (cum + (unsigned)__popcll(eq & lmlt) < rem)));
        cum += (unsigned)__popcll(eq);
        selg = incau && (!mid || hv);
      }
      if (selg) mx = fmaxf(mx, s);
    }
#pragma unroll
    for (int off = 32; off; off >>= 1) mx = fmaxf(mx, __shfl_xor(mx, off, 64));

    float sum = 0.f;
    cum = 0;
#pragma unroll 1
    for (int c0 = 0; c0 < nkm; c0 += 64) {
      int ki = c0 + lane;
      bool incau = ki <= qi;
      float s = sc[r][ki];
      bool selg;
      if (!need) {
        selg = incau;
      } else {
        bool mid = incau && (ki >= INIT_N) && (ki <= mhi);
        unsigned kk = fkey(s);
        unsigned long long eq = __ballot(mid && (kk == T));
        bool hv = mid && ((kk > T) ||
                          ((kk == T) && (cum + (unsigned)__popcll(eq & lmlt) < rem)));
        cum += (unsigned)__popcll(eq);
        selg = incau && (!mid || hv);
      }
      float e = selg ? __expf(s - mx) : 0.f;
      sum += e;
      if (ki < nkm) sc[r][ki] = e;
    }
#pragma unroll
    for (int off = 32; off; off >>= 1) sum += __shfl_xor(sum, off, 64);
    if (lane == 0) sumv[r] = sum;
  }
  __syncthreads();

  const int d2 = lane << 1;
  const float* vb = v + (size_t)g * HD + d2;
  float a00 = 0.f, a01 = 0.f, a10 = 0.f, a11 = 0.f;
  float a20 = 0.f, a21 = 0.f, a30 = 0.f, a31 = 0.f;
#pragma unroll 2
  for (int ki = wid; ki < nkm; ki += 4) {
    float p0 = sc[0][ki], p1 = sc[1][ki], p2 = sc[2][ki], p3 = sc[3][ki];
    if ((p0 != 0.f) || (p1 != 0.f) || (p2 != 0.f) || (p3 != 0.f)) {
      float2 v2 = *(const float2*)(vb + (size_t)ki * (NKV * HD));
      a00 = fmaf(p0, v2.x, a00); a01 = fmaf(p0, v2.y, a01);
      a10 = fmaf(p1, v2.x, a10); a11 = fmaf(p1, v2.y, a11);
      a20 = fmaf(p2, v2.x, a20); a21 = fmaf(p2, v2.y, a21);
      a30 = fmaf(p3, v2.x, a30); a31 = fmaf(p3, v2.y, a31);
    }
  }
  __syncthreads();

  float* pvred = &sc[0][0];
  {
    const int base = (wid * 4) << 7;
    *(float2*)&pvred[base + (0 << 7) + d2] = make_float2(a00, a01);
    *(float2*)&pvred[base + (1 << 7) + d2] = make_float2(a10, a11);
    *(float2*)&pvred[base + (2 << 7) + d2] = make_float2(a20, a21);
    *(float2*)&pvred[base + (3 << 7) + d2] = make_float2(a30, a31);
  }
  __syncthreads();

#pragma unroll
  for (int it = 0; it < 2; ++it) {
    int o = it * 256 + tid;
    int r = o >> 7;
    int d = o & 127;
    float vs = pvred[((0 * 4 + r) << 7) + d] + pvred[((1 * 4 + r) << 7) + d] +
               pvred[((2 * 4 + r) << 7) + d] + pvred[((3 * 4 + r) << 7) + d];
    ao[((size_t)(qi0 + r) * NH + h) * HD + d] = vs / sumv[r];
  }
}

// ---------------------------------------------------------------------------
extern "C" void kernel_launch(void* const* d_in, const int* in_sizes, int n_in,
                              void* d_out, int out_size, void* d_ws, size_t ws_size,
                              hipStream_t stream) {
  const float* hidden = (const float*)d_in[0];
  const float* wq = (const float*)d_in[1];
  const float* wk = (const float*)d_in[2];
  const float* wv = (const float*)d_in[3];
  const float* wo = (const float*)d_in[4];
  float* out = (float*)d_out;

  // workspace layout (floats): total 33,554,432 floats = 128 MB
  float* ws = (float*)d_ws;
  float* q     = ws;                          // 8,388,608 floats [S][NH*HD]
  float* aoReg = q + (size_t)8388608;         // 8,388,608 floats (ao; overlays kbuf/wkT/wvT)
  float* kbuf  = aoReg;                       // 2,097,152 floats [S][NKV*HD]
  unsigned short* wkT = (unsigned short*)(aoReg + 2097152);  // [1024][4096] bf16
  unsigned short* wvT = (unsigned short*)(aoReg + 4194304);  // [1024][4096] bf16
  float* vbuf  = aoReg + (size_t)8388608;     // 2,097,152 floats
  float* kT    = vbuf + (size_t)2097152;      // 2,097,152 floats [g][d][s]
  unsigned short* hb  = (unsigned short*)(kT + 2097152);     // [S][HID] bf16 (aob overlays)
  unsigned short* aob = hb;
  unsigned short* wTb = (unsigned short*)(kT + 2097152 + 4194304);  // [4096][4096] bf16

  dim3 blk(256);
  const int NE = S_LEN * HID_N;  // 8,388,608

  cast_bf16x8<<<NE / 2048, blk, 0, stream>>>(hidden, hb, NE);
  transpose_cast<<<dim3(HID_N / 64, HID_N / 64), blk, 0, stream>>>(wq, wTb, HID_N, NH * HD);
  transpose_cast<<<dim3((NKV * HD) / 64, HID_N / 64), blk, 0, stream>>>(wk, wkT, HID_N, NKV * HD);
  transpose_cast<<<dim3((NKV * HD) / 64, HID_N / 64), blk, 0, stream>>>(wv, wvT, HID_N, NKV * HD);

  gemm_bf16<<<dim3((NH * HD) / 128, S_LEN / 128), blk, 0, stream>>>(hb, wTb, q, S_LEN, NH * HD, HID_N);
  gemm_bf16<<<dim3((NKV * HD) / 128, S_LEN / 128), blk, 0, stream>>>(hb, wkT, kbuf, S_LEN, NKV * HD, HID_N);
  gemm_bf16<<<dim3((NKV * HD) / 128, S_LEN / 128), blk, 0, stream>>>(hb, wvT, vbuf, S_LEN, NKV * HD, HID_N);

  transpose_cast<<<dim3(HID_N / 64, (NH * HD) / 64), blk, 0, stream>>>(wo, wTb, NH * HD, HID_N);

  rope_f32<<<(S_LEN * NH * 64) / 256, blk, 0, stream>>>(q, NH);
  transpose_rope_k<<<dim3(S_LEN / 64, NKV), blk, 0, stream>>>(kbuf, kT);

  attn_kernel<<<dim3(S_LEN / TQ, NH), blk, 0, stream>>>(q, kT, vbuf, aoReg);

  cast_bf16x8<<<NE / 2048, blk, 0, stream>>>(aoReg, aob, NE);
  gemm_bf16<<<dim3(HID_N / 128, S_LEN / 128), blk, 0, stream>>>(aob, wTb, out, S_LEN, HID_N, NH * HD);
}